// Round 1
// baseline (218.692 us; speedup 1.0000x reference)
//
#include <hip/hip_runtime.h>
#include <cstdint>

typedef __attribute__((ext_vector_type(8))) short bf16x8_t;
typedef __attribute__((ext_vector_type(4))) float f32x4_t;

#define T_SEQ 2048
#define NHEAD 16
#define CDIM  1024

__device__ __forceinline__ unsigned short f2bf(float f) {
  union { float f; unsigned u; } v; v.f = f;
  unsigned r = v.u + 0x7FFFu + ((v.u >> 16) & 1u);
  return (unsigned short)(r >> 16);
}

__device__ __forceinline__ void gload_lds16(const void* g, void* l) {
  typedef const uint32_t __attribute__((address_space(1)))* gp_t;
  typedef uint32_t __attribute__((address_space(3)))* lp_t;
  __builtin_amdgcn_global_load_lds((gp_t)(uintptr_t)g, (lp_t)(uint32_t)(uintptr_t)l, 16, 0, 0);
}

// ---------------- f32 -> bf16 elementwise ----------------
__global__ void conv_bf16_kernel(const float* __restrict__ in,
                                 unsigned short* __restrict__ out, int n4) {
  int i = blockIdx.x * blockDim.x + threadIdx.x;
  if (i >= n4) return;
  float4 v = ((const float4*)in)[i];
  ushort4 o;
  o.x = f2bf(v.x); o.y = f2bf(v.y); o.z = f2bf(v.z); o.w = f2bf(v.w);
  ((ushort4*)out)[i] = o;
}

// ---------------- transpose f32 [R][C] -> bf16 [C][R] ----------------
__global__ void transpose_bf16_kernel(const float* __restrict__ W,
                                      unsigned short* __restrict__ WT, int R, int C) {
  __shared__ unsigned short tile[64][65];
  const int c0 = blockIdx.x * 64, r0 = blockIdx.y * 64;
  const int t = threadIdx.x;
  #pragma unroll
  for (int i = 0; i < 16; i++) {
    int idx = i * 256 + t;
    int r = idx >> 6, c = idx & 63;
    tile[r][c] = f2bf(W[(size_t)(r0 + r) * C + c0 + c]);
  }
  __syncthreads();
  #pragma unroll
  for (int i = 0; i < 16; i++) {
    int idx = i * 256 + t;
    int c = idx >> 6, r = idx & 63;
    WT[(size_t)(c0 + c) * R + r0 + r] = tile[r][c];
  }
}

// ---------------- GEMM: A[M][K] bf16 x Bt[N][K] bf16 -> epilogue ----------------
// MODE 0: qkv projection. out scatters to q[BH][T][64] (x0.125), k[BH][T][64], vT[BH][64][T], bias added.
// MODE 1: proj. c_out[M][N] fp32 = A@B + bias.
template <int MODE>
__global__ void gemm_bt_kernel(const unsigned short* __restrict__ A,
                               const unsigned short* __restrict__ Bt,
                               const float* __restrict__ bias,
                               unsigned short* __restrict__ q_out,
                               unsigned short* __restrict__ k_out,
                               unsigned short* __restrict__ v_out,
                               float* __restrict__ c_out,
                               int K, int N) {
  const int t = threadIdx.x;
  const int w = t >> 6, l = t & 63;
  const int lr = l & 15, lg = l >> 4;
  const int wr = w >> 1, wc = w & 1;
  const int m0 = blockIdx.y * 128, n0 = blockIdx.x * 128;

  __shared__ __align__(16) unsigned short As[128 * 64];
  __shared__ __align__(16) unsigned short Bs[128 * 64];

  f32x4_t acc[4][4];
  #pragma unroll
  for (int mi = 0; mi < 4; mi++)
    #pragma unroll
    for (int ni = 0; ni < 4; ni++)
      acc[mi][ni] = (f32x4_t){0.f, 0.f, 0.f, 0.f};

  const int srow = t >> 3;          // 0..31
  const int scol = (t & 7) * 8;     // element col (16B chunks)
  const size_t abase = (size_t)(m0 + srow) * K + scol;
  const size_t bbase = (size_t)(n0 + srow) * K + scol;

  for (int k0 = 0; k0 < K; k0 += 64) {
    __syncthreads();
    #pragma unroll
    for (int i = 0; i < 4; i++) {
      gload_lds16(A + abase + (size_t)i * 32 * K + k0, &As[(i * 32 + srow) * 64 + scol]);
      gload_lds16(Bt + bbase + (size_t)i * 32 * K + k0, &Bs[(i * 32 + srow) * 64 + scol]);
    }
    __syncthreads();
    #pragma unroll
    for (int ks = 0; ks < 2; ks++) {
      bf16x8_t af[4], bfr[4];
      #pragma unroll
      for (int mi = 0; mi < 4; mi++)
        af[mi] = *(const bf16x8_t*)&As[(wr * 64 + mi * 16 + lr) * 64 + ks * 32 + lg * 8];
      #pragma unroll
      for (int ni = 0; ni < 4; ni++)
        bfr[ni] = *(const bf16x8_t*)&Bs[(wc * 64 + ni * 16 + lr) * 64 + ks * 32 + lg * 8];
      #pragma unroll
      for (int mi = 0; mi < 4; mi++)
        #pragma unroll
        for (int ni = 0; ni < 4; ni++)
          acc[mi][ni] = __builtin_amdgcn_mfma_f32_16x16x32_bf16(af[mi], bfr[ni], acc[mi][ni], 0, 0, 0);
    }
  }

  if (MODE == 0) {
    #pragma unroll
    for (int ni = 0; ni < 4; ni++) {
      const int n = n0 + wc * 64 + ni * 16 + lr;
      const float bv = bias[n];
      const int s = n >> 10;           // 0:q 1:k 2:v
      const int hh = (n >> 6) & 15;    // head
      const int d = n & 63;            // dim in head
      #pragma unroll
      for (int mi = 0; mi < 4; mi++) {
        const int mbase = m0 + wr * 64 + mi * 16 + lg * 4;
        const int batch = mbase >> 11;
        const int tt = mbase & 2047;
        const int bhh = batch * NHEAD + hh;
        if (s == 0) {
          #pragma unroll
          for (int r = 0; r < 4; r++)
            q_out[((size_t)bhh * T_SEQ + tt + r) * 64 + d] = f2bf((acc[mi][ni][r] + bv) * 0.125f);
        } else if (s == 1) {
          #pragma unroll
          for (int r = 0; r < 4; r++)
            k_out[((size_t)bhh * T_SEQ + tt + r) * 64 + d] = f2bf(acc[mi][ni][r] + bv);
        } else {
          ushort4 pk;
          pk.x = f2bf(acc[mi][ni][0] + bv);
          pk.y = f2bf(acc[mi][ni][1] + bv);
          pk.z = f2bf(acc[mi][ni][2] + bv);
          pk.w = f2bf(acc[mi][ni][3] + bv);
          *(ushort4*)&v_out[((size_t)bhh * 64 + d) * T_SEQ + tt] = pk;
        }
      }
    }
  } else {
    #pragma unroll
    for (int ni = 0; ni < 4; ni++) {
      const int n = n0 + wc * 64 + ni * 16 + lr;
      const float bv = bias[n];
      #pragma unroll
      for (int mi = 0; mi < 4; mi++) {
        const int m = m0 + wr * 64 + mi * 16 + lg * 4;
        #pragma unroll
        for (int r = 0; r < 4; r++)
          c_out[(size_t)(m + r) * N + n] = acc[mi][ni][r] + bv;
      }
    }
  }
}

// ---------------- causal flash attention ----------------
// Q[BH][T][64] bf16 (pre-scaled by 1/8), K[BH][T][64] bf16, Vt[BH][64][T] bf16
// O[B][T][C] bf16 (attention output, pre-projection)
__global__ void attn_kernel(const unsigned short* __restrict__ Qb,
                            const unsigned short* __restrict__ Kb,
                            const unsigned short* __restrict__ Vt,
                            unsigned short* __restrict__ O) {
  const int qblk = blockIdx.x, bh = blockIdx.y;
  const int batch = bh >> 4, h = bh & 15;
  const int q0 = qblk * 128;
  const int t = threadIdx.x;
  const int w = t >> 6, l = t & 63;
  const int lr = l & 15, lg = l >> 4;
  const int wq0 = q0 + w * 32;

  __shared__ __align__(16) unsigned short Ks[64 * 72];
  __shared__ __align__(16) unsigned short Vs[64 * 72];
  __shared__ __align__(16) unsigned short Ps[4][32 * 72];

  // Q fragments held in registers for whole KV loop
  bf16x8_t qf[2][2];
  #pragma unroll
  for (int mi = 0; mi < 2; mi++)
    #pragma unroll
    for (int ks = 0; ks < 2; ks++)
      qf[mi][ks] = *(const bf16x8_t*)&Qb[((size_t)bh * T_SEQ + wq0 + mi * 16 + lr) * 64 + ks * 32 + lg * 8];

  f32x4_t acc_o[2][4];
  float m_run[2][4], l_run[2][4];
  #pragma unroll
  for (int mi = 0; mi < 2; mi++) {
    #pragma unroll
    for (int di = 0; di < 4; di++) acc_o[mi][di] = (f32x4_t){0.f, 0.f, 0.f, 0.f};
    #pragma unroll
    for (int r = 0; r < 4; r++) { m_run[mi][r] = -1e30f; l_run[mi][r] = 0.f; }
  }

  const int srow = t >> 3, scol = (t & 7) * 8;

  for (int kv0 = 0; kv0 < q0 + 128; kv0 += 64) {
    __syncthreads();
    // reg-staged, padded LDS tiles (stride 72 bf16 = 144B -> 2-way conflicts only)
    #pragma unroll
    for (int i = 0; i < 2; i++) {
      int row = i * 32 + srow;
      *(bf16x8_t*)&Ks[row * 72 + scol] =
          *(const bf16x8_t*)&Kb[((size_t)bh * T_SEQ + kv0 + row) * 64 + scol];
      *(bf16x8_t*)&Vs[row * 72 + scol] =
          *(const bf16x8_t*)&Vt[((size_t)bh * 64 + row) * T_SEQ + kv0 + scol];
    }
    __syncthreads();

    if (kv0 <= wq0 + 31) {   // wave has at least one unmasked element in this tile
      // S = Q K^T (pre-scaled)
      f32x4_t sc4[2][4];
      #pragma unroll
      for (int mi = 0; mi < 2; mi++)
        #pragma unroll
        for (int ni = 0; ni < 4; ni++)
          sc4[mi][ni] = (f32x4_t){0.f, 0.f, 0.f, 0.f};
      #pragma unroll
      for (int ks = 0; ks < 2; ks++) {
        bf16x8_t bk[4];
        #pragma unroll
        for (int ni = 0; ni < 4; ni++)
          bk[ni] = *(const bf16x8_t*)&Ks[(ni * 16 + lr) * 72 + ks * 32 + lg * 8];
        #pragma unroll
        for (int mi = 0; mi < 2; mi++)
          #pragma unroll
          for (int ni = 0; ni < 4; ni++)
            sc4[mi][ni] = __builtin_amdgcn_mfma_f32_16x16x32_bf16(qf[mi][ks], bk[ni], sc4[mi][ni], 0, 0, 0);
      }
      // causal mask (kv > q)
      if (kv0 + 63 > wq0) {
        #pragma unroll
        for (int mi = 0; mi < 2; mi++)
          #pragma unroll
          for (int ni = 0; ni < 4; ni++)
            #pragma unroll
            for (int r = 0; r < 4; r++)
              if (kv0 + ni * 16 + lr > wq0 + mi * 16 + lg * 4 + r) sc4[mi][ni][r] = -1e30f;
      }
      // online softmax per m-block
      #pragma unroll
      for (int mi = 0; mi < 2; mi++) {
        float mx[4], ps[4], nm[4], scal[4];
        #pragma unroll
        for (int r = 0; r < 4; r++)
          mx[r] = fmaxf(fmaxf(sc4[mi][0][r], sc4[mi][1][r]), fmaxf(sc4[mi][2][r], sc4[mi][3][r]));
        #pragma unroll
        for (int off = 8; off >= 1; off >>= 1)
          #pragma unroll
          for (int r = 0; r < 4; r++)
            mx[r] = fmaxf(mx[r], __shfl_xor(mx[r], off, 64));
        #pragma unroll
        for (int r = 0; r < 4; r++) {
          nm[r] = fmaxf(m_run[mi][r], mx[r]);
          scal[r] = __expf(m_run[mi][r] - nm[r]);
          m_run[mi][r] = nm[r];
          ps[r] = 0.f;
        }
        #pragma unroll
        for (int ni = 0; ni < 4; ni++)
          #pragma unroll
          for (int r = 0; r < 4; r++) {
            float p = __expf(sc4[mi][ni][r] - nm[r]);
            sc4[mi][ni][r] = p;
            ps[r] += p;
          }
        #pragma unroll
        for (int off = 8; off >= 1; off >>= 1)
          #pragma unroll
          for (int r = 0; r < 4; r++)
            ps[r] += __shfl_xor(ps[r], off, 64);
        #pragma unroll
        for (int r = 0; r < 4; r++)
          l_run[mi][r] = l_run[mi][r] * scal[r] + ps[r];
        #pragma unroll
        for (int di = 0; di < 4; di++)
          #pragma unroll
          for (int r = 0; r < 4; r++)
            acc_o[mi][di][r] *= scal[r];
        // P -> per-wave LDS (A-fragment layout source)
        #pragma unroll
        for (int ni = 0; ni < 4; ni++)
          #pragma unroll
          for (int r = 0; r < 4; r++)
            Ps[w][(mi * 16 + lg * 4 + r) * 72 + ni * 16 + lr] = f2bf(sc4[mi][ni][r]);
      }
      asm volatile("s_waitcnt lgkmcnt(0)" ::: "memory");
      // O += P V
      #pragma unroll
      for (int kv = 0; kv < 2; kv++) {
        bf16x8_t pa[2], bv[4];
        #pragma unroll
        for (int mi = 0; mi < 2; mi++)
          pa[mi] = *(const bf16x8_t*)&Ps[w][(mi * 16 + lr) * 72 + kv * 32 + lg * 8];
        #pragma unroll
        for (int di = 0; di < 4; di++)
          bv[di] = *(const bf16x8_t*)&Vs[(di * 16 + lr) * 72 + kv * 32 + lg * 8];
        #pragma unroll
        for (int mi = 0; mi < 2; mi++)
          #pragma unroll
          for (int di = 0; di < 4; di++)
            acc_o[mi][di] = __builtin_amdgcn_mfma_f32_16x16x32_bf16(pa[mi], bv[di], acc_o[mi][di], 0, 0, 0);
      }
    }
  }

  // epilogue: O[b][t][h*64+d] = acc / l
  #pragma unroll
  for (int mi = 0; mi < 2; mi++)
    #pragma unroll
    for (int di = 0; di < 4; di++)
      #pragma unroll
      for (int r = 0; r < 4; r++) {
        int tt = wq0 + mi * 16 + lg * 4 + r;
        float vv = acc_o[mi][di][r] / l_run[mi][r];
        O[((size_t)batch * T_SEQ + tt) * CDIM + h * 64 + di * 16 + lr] = f2bf(vv);
      }
}

extern "C" void kernel_launch(void* const* d_in, const int* in_sizes, int n_in,
                              void* d_out, int out_size, void* d_ws, size_t ws_size,
                              hipStream_t stream) {
  (void)in_sizes; (void)n_in; (void)out_size; (void)ws_size;
  const float* x      = (const float*)d_in[0];
  const float* w_qkv  = (const float*)d_in[1];
  const float* b_qkv  = (const float*)d_in[2];
  const float* w_proj = (const float*)d_in[3];
  const float* b_proj = (const float*)d_in[4];
  float* out = (float*)d_out;

  char* ws = (char*)d_ws;
  unsigned short* xb     = (unsigned short*)(ws);                       // 8 MB  x bf16 [4096][1024]
  unsigned short* wqkvT  = (unsigned short*)(ws + ((size_t)8  << 20));  // 6 MB  [3072][1024]
  unsigned short* wprojT = (unsigned short*)(ws + ((size_t)14 << 20));  // 2 MB  [1024][1024]
  unsigned short* qb     = (unsigned short*)(ws + ((size_t)16 << 20));  // 8 MB  [32][2048][64]
  unsigned short* kb     = (unsigned short*)(ws + ((size_t)24 << 20));  // 8 MB  [32][2048][64]
  unsigned short* vtb    = (unsigned short*)(ws + ((size_t)32 << 20));  // 8 MB  [32][64][2048]
  unsigned short* ab     = (unsigned short*)(ws + ((size_t)40 << 20));  // 8 MB  attn out [4096][1024]

  conv_bf16_kernel<<<4096, 256, 0, stream>>>(x, xb, (2 * T_SEQ * CDIM) / 4);
  transpose_bf16_kernel<<<dim3(48, 16), 256, 0, stream>>>(w_qkv, wqkvT, 1024, 3072);
  transpose_bf16_kernel<<<dim3(16, 16), 256, 0, stream>>>(w_proj, wprojT, 1024, 1024);
  gemm_bt_kernel<0><<<dim3(24, 32), 256, 0, stream>>>(xb, wqkvT, b_qkv, qb, kb, vtb, nullptr, 1024, 3072);
  attn_kernel<<<dim3(16, 32), 256, 0, stream>>>(qb, kb, vtb, ab);
  gemm_bt_kernel<1><<<dim3(8, 32), 256, 0, stream>>>(ab, wprojT, b_proj, nullptr, nullptr, nullptr, out, 1024, 1024);
}